// Round 6
// baseline (152.528 us; speedup 1.0000x reference)
//
#include <hip/hip_runtime.h>

#define EMBED 256
#define NUM_DEPTH 128
#define CT_STRIDE 136   // 128 + 8 pad: 16B-aligned rows, breaks pow-2 bank stride

typedef __attribute__((ext_vector_type(8))) short bf16x8;
typedef __attribute__((ext_vector_type(4))) float f32x4;

__device__ __forceinline__ unsigned short f2b(float f) {
    union { float f; unsigned u; } c; c.f = f;
    unsigned u = c.u;
    u += 0x7fffu + ((u >> 16) & 1u);   // RNE to bf16
    return (unsigned short)(u >> 16);
}
__device__ __forceinline__ float b2f(unsigned short h) {
    union { unsigned u; float f; } c; c.u = ((unsigned)h) << 16;
    return c.f;
}

// -------- Phase 1: fp32 -> bf16 conversion of key & value, plus out = identity ----
__global__ __launch_bounds__(256) void cvt_init_kernel(
    const float4* __restrict__ key, const float4* __restrict__ val,
    ushort4* __restrict__ kb, ushort4* __restrict__ vb, int n4,
    const float4* __restrict__ id4, float4* __restrict__ out4, int nid4)
{
    int i = blockIdx.x * blockDim.x + threadIdx.x;
    if (i < n4) {
        float4 a = key[i];
        float4 b = val[i];
        kb[i] = make_ushort4(f2b(a.x), f2b(a.y), f2b(a.z), f2b(a.w));
        vb[i] = make_ushort4(f2b(b.x), f2b(b.y), f2b(b.z), f2b(b.w));
    }
    if (i < nid4) out4[i] = id4[i];   // out pre-init (harness poisons d_out each call)
}

// -------- Phase 2: fused GEMM + bilinear scatter ----------------------------------
// Block (jt=blockIdx.x, i=blockIdx.y): C-tile = key[128i..) x value[128jt..)^T into
// padded LDS (bf16), then a brute-force scan over the block's 128q x 128d pairs:
// any pair whose bilinear tap rows intersect this tile's image rows adds
// w * C / 16 into out via atomicAdd (out pre-set to identity; <=2 atomics/element).
__global__ __launch_bounds__(256) void gemm_scatter_kernel(
    const unsigned short* __restrict__ A,   // kb [nq][256]
    const unsigned short* __restrict__ B,   // vb [nv][256]
    const float* __restrict__ ref3d,        // [nq*128][2]
    const int*   __restrict__ spatial,      // {H, W}
    float* __restrict__ out)                // [nq*128], pre-initialized
{
    __shared__ __align__(16) unsigned short Ct[128 * CT_STRIDE];  // 34816 B
    unsigned short* As = Ct;              // 128x32 = 8 KB (dead after K-loop)
    unsigned short* Bs = Ct + 128 * 32;   // next 8 KB

    const int m0 = blockIdx.y * 128;      // q base
    const int jt = blockIdx.x;            // p-tile index
    const int n0 = jt * 128;              // p base
    const int tid  = threadIdx.x;
    const int lane = tid & 63;
    const int wave = tid >> 6;
    const int wm = (wave & 1) * 64;
    const int wn = (wave >> 1) * 64;

    f32x4 acc[4][4] = {};

    const int srow = lane >> 2;
    const int scol = (lane & 3) * 8;
    const int k8 = (lane >> 4) * 8;
    const int fm = lane & 15;

    // ---- K-loop: exact R4 structure (validated at 99 us) ----
    for (int kt = 0; kt < EMBED; kt += 32) {
        #pragma unroll
        for (int t = 0; t < 2; ++t) {
            const int c = wave * 2 + t;
            const int row = c * 16 + srow;
            const unsigned short* ga = A + (size_t)(m0 + row) * EMBED + kt + scol;
            const unsigned short* gb = B + (size_t)(n0 + row) * EMBED + kt + scol;
            __builtin_amdgcn_global_load_lds(
                (const __attribute__((address_space(1))) void*)ga,
                (__attribute__((address_space(3))) void*)(As + c * 512), 16, 0, 0);
            __builtin_amdgcn_global_load_lds(
                (const __attribute__((address_space(1))) void*)gb,
                (__attribute__((address_space(3))) void*)(Bs + c * 512), 16, 0, 0);
        }
        __syncthreads();

        bf16x8 af[4], bfr[4];
        #pragma unroll
        for (int i = 0; i < 4; ++i) {
            af[i]  = *(const bf16x8*)(As + (wm + i * 16 + fm) * 32 + k8);
            bfr[i] = *(const bf16x8*)(Bs + (wn + i * 16 + fm) * 32 + k8);
        }
        #pragma unroll
        for (int i = 0; i < 4; ++i)
            #pragma unroll
            for (int j = 0; j < 4; ++j)
                acc[i][j] = __builtin_amdgcn_mfma_f32_16x16x32_bf16(af[i], bfr[j], acc[i][j], 0, 0, 0);
        __syncthreads();   // As/Bs dead after this -> Ct overwrite below is safe
    }

    // ---- Epilogue: fragments -> Ct (bf16). C/D layout: col=lane&15, row=(lane>>4)*4+r
    const int col = lane & 15;
    const int rbase = (lane >> 4) * 4;
    #pragma unroll
    for (int i = 0; i < 4; ++i)
        #pragma unroll
        for (int j = 0; j < 4; ++j) {
            const int rr = wm + i * 16 + rbase;
            const int cc = wn + j * 16 + col;
            #pragma unroll
            for (int r = 0; r < 4; ++r)
                Ct[(rr + r) * CT_STRIDE + cc] = f2b(acc[i][j][r]);
        }
    __syncthreads();

    // ---- Scatter scan: 16384 (q_local, d) pairs, 64 per thread ----
    const int H = spatial[0], W = spatial[1];
    const int Rt = 128 / W;               // image rows per p-tile (2 for W=64)
    const int iy_lo = Rt * jt;
    const float2* __restrict__ r3 = (const float2*)ref3d;

    for (int e = tid; e < 128 * NUM_DEPTH; e += 256) {
        const int ql = e >> 7;                       // q_local 0..127
        const int l = (m0 + ql) * NUM_DEPTH + (e & 127);
        const float2 r2 = r3[l];                     // coalesced; L2-resident (4 MB)
        const float px = r2.x * (float)W - 0.5f;
        const float py = r2.y * (float)H - 0.5f;
        const float x0f = floorf(px), y0f = floorf(py);
        const int iy0 = (int)y0f;
        // quick reject: neither tap row in [iy_lo, iy_lo+Rt)
        if (iy0 + 1 < iy_lo || iy0 >= iy_lo + Rt) continue;

        const int ix0 = (int)x0f;
        const float wx1 = px - x0f, wx0 = 1.0f - wx1;
        const float wy1 = py - y0f, wy0 = 1.0f - wy1;
        const bool vx0 = (ix0 >= 0) & (ix0 < W);
        const bool vx1 = (ix0 + 1 >= 0) & (ix0 + 1 < W);

        float accv = 0.f;
        bool hit = false;
        #pragma unroll
        for (int ky = 0; ky < 2; ++ky) {
            const int iy = iy0 + ky;
            if (iy < iy_lo || iy >= iy_lo + Rt) continue;   // also rejects iy<0, iy>=H
            const float wy = ky ? wy1 : wy0;
            const int pb = ql * CT_STRIDE + (iy - iy_lo) * W;
            if (vx0) { accv = fmaf(wy * wx0, b2f(Ct[pb + ix0]), accv); hit = true; }
            if (vx1) { accv = fmaf(wy * wx1, b2f(Ct[pb + ix0 + 1]), accv); hit = true; }
        }
        if (hit)
            atomicAdd(&out[l], accv * 0.0625f);   // 1/sqrt(256) = 1/16
    }
}

// ---------------- Fallback (round-1 direct kernel) ----------------
__global__ __launch_bounds__(256) void uv_direct_kernel(
    const float* __restrict__ key, const float* __restrict__ value,
    const float* __restrict__ identity, const float* __restrict__ ref3d,
    const int* __restrict__ spatial, float* __restrict__ out)
{
    const int q = blockIdx.x;
    const int tid = threadIdx.x;
    const int lane = tid & 63;
    const int wave = tid >> 6;
    const int H = spatial[0], W = spatial[1];
    const int row4 = EMBED / 4;
    const float4 k4 = reinterpret_cast<const float4*>(key + (size_t)q * EMBED)[lane];
    const float4* __restrict__ v4 = reinterpret_cast<const float4*>(value);
    for (int d = wave; d < NUM_DEPTH; d += 4) {
        const int l = q * NUM_DEPTH + d;
        const float rx = ref3d[2 * l], ry = ref3d[2 * l + 1];
        const float px = rx * (float)W - 0.5f, py = ry * (float)H - 0.5f;
        const float x0f = floorf(px), y0f = floorf(py);
        const int ix0 = (int)x0f, iy0 = (int)y0f, ix1 = ix0 + 1, iy1 = iy0 + 1;
        const float wx1 = px - x0f, wx0 = 1.f - wx1, wy1 = py - y0f, wy0 = 1.f - wy1;
        float4 acc = make_float4(0.f, 0.f, 0.f, 0.f);
        #define TAP(IY, IX, WGT) \
            if ((IY) >= 0 && (IY) < H && (IX) >= 0 && (IX) < W) { \
                const float w_ = (WGT); \
                const float4 t = v4[(size_t)((IY) * W + (IX)) * row4 + lane]; \
                acc.x = fmaf(w_, t.x, acc.x); acc.y = fmaf(w_, t.y, acc.y); \
                acc.z = fmaf(w_, t.z, acc.z); acc.w = fmaf(w_, t.w, acc.w); }
        TAP(iy0, ix0, wy0 * wx0) TAP(iy0, ix1, wy0 * wx1)
        TAP(iy1, ix0, wy1 * wx0) TAP(iy1, ix1, wy1 * wx1)
        #undef TAP
        float partial = acc.x * k4.x + acc.y * k4.y + acc.z * k4.z + acc.w * k4.w;
        #pragma unroll
        for (int off = 32; off > 0; off >>= 1) partial += __shfl_xor(partial, off, 64);
        if (lane == 0) out[l] = fmaf(partial, 0.0625f, identity[l]);
    }
}

extern "C" void kernel_launch(void* const* d_in, const int* in_sizes, int n_in,
                              void* d_out, int out_size, void* d_ws, size_t ws_size,
                              hipStream_t stream) {
    // inputs: 0 query(unused) 1 key 2 value 3 identity 4 ref_3d 5 spatial 6 W_attn(unused) 7 b_attn(unused)
    const float* key      = (const float*)d_in[1];
    const float* value    = (const float*)d_in[2];
    const float* identity = (const float*)d_in[3];
    const float* ref3d    = (const float*)d_in[4];
    const int*   spatial  = (const int*)d_in[5];
    float* out = (float*)d_out;

    const int nq = in_sizes[3] / NUM_DEPTH;   // 4096 queries
    const int nv = in_sizes[1] / EMBED;       // 4096 pixels (= H*W)

    const size_t kb_bytes = (size_t)nq * EMBED * sizeof(unsigned short);
    const size_t vb_bytes = (size_t)nv * EMBED * sizeof(unsigned short);
    const size_t need = kb_bytes + vb_bytes;

    if (ws_size < need || (nq % 128) || (nv % 128)) {
        uv_direct_kernel<<<nq, 256, 0, stream>>>(key, value, identity, ref3d, spatial, out);
        return;
    }

    unsigned short* kb = (unsigned short*)d_ws;
    unsigned short* vb = (unsigned short*)((char*)d_ws + kb_bytes);

    // Phase 1: convert key & value to bf16; out = identity
    const int n4   = nq * EMBED / 4;
    const int nid4 = nq * NUM_DEPTH / 4;
    cvt_init_kernel<<<(n4 + 255) / 256, 256, 0, stream>>>(
        (const float4*)key, (const float4*)value, (ushort4*)kb, (ushort4*)vb, n4,
        (const float4*)identity, (float4*)out, nid4);

    // Phase 2: fused GEMM + bilinear scatter-accumulate
    dim3 grid(nv / 128, nq / 128);
    gemm_scatter_kernel<<<grid, 256, 0, stream>>>(kb, vb, ref3d, spatial, out);
}

// Round 7
// 99.036 us; speedup vs baseline: 1.5401x; 1.5401x over previous
//
#include <hip/hip_runtime.h>

#define EMBED 256
#define NUM_DEPTH 128
#define CT_STRIDE 136   // 128 + 8 pad: 16B-aligned rows, breaks pow-2 bank stride

typedef __attribute__((ext_vector_type(8))) short bf16x8;
typedef __attribute__((ext_vector_type(4))) float f32x4;

__device__ __forceinline__ unsigned short f2b(float f) {
    union { float f; unsigned u; } c; c.f = f;
    unsigned u = c.u;
    u += 0x7fffu + ((u >> 16) & 1u);   // RNE to bf16
    return (unsigned short)(u >> 16);
}
__device__ __forceinline__ float b2f(unsigned short h) {
    union { unsigned u; float f; } c; c.u = ((unsigned)h) << 16;
    return c.f;
}

// ---------------- Phase 1: fp32 -> bf16 conversion of key & value ----------------
__global__ __launch_bounds__(256) void cvt_kernel(
    const float4* __restrict__ key, const float4* __restrict__ val,
    ushort4* __restrict__ kb, ushort4* __restrict__ vb, int n4)
{
    int i = blockIdx.x * blockDim.x + threadIdx.x;
    if (i >= n4) return;
    float4 a = key[i];
    float4 b = val[i];
    kb[i] = make_ushort4(f2b(a.x), f2b(a.y), f2b(a.z), f2b(a.w));
    vb[i] = make_ushort4(f2b(b.x), f2b(b.y), f2b(b.z), f2b(b.w));
}

// ---------------- Phase 2: D[q][p] = sum_e key[q,e]*value[p,e]  (NT GEMM) --------
// 128x128 tile, 256 threads (4 waves 2x2), 16x16x32 bf16 MFMA, BK=64.
// Staging keeps R4's coalesced lane mapping (4 lanes cover one 64B line):
// chunk c = 16 rows; lane -> row c*16+(lane>>2), cols (lane&3)*8.
// LDS layout [c][h][row][col8] (h = 32-wide k-half); fragment reads pick h=kk.
// 8 barrier-drains total (vs 16 at BK=32).
__global__ __launch_bounds__(256) void gemm_nt_bf16(
    const unsigned short* __restrict__ A,   // key bf16 [M][256]
    const unsigned short* __restrict__ B,   // value bf16 [N][256]
    unsigned short* __restrict__ D,         // [M][N] bf16
    int N)
{
    __shared__ __align__(16) unsigned short Ct[128 * CT_STRIDE];  // 34816 B
    unsigned short* As = Ct;              // 8 chunks * 1024 elems = 16 KB
    unsigned short* Bs = Ct + 8192;       // 16 KB (total 32 KB, aliased in Ct)

    const int m0 = blockIdx.y * 128;
    const int n0 = blockIdx.x * 128;
    const int tid  = threadIdx.x;
    const int lane = tid & 63;
    const int wave = tid >> 6;
    const int wm = (wave & 1) * 64;
    const int wn = (wave >> 1) * 64;

    f32x4 acc[4][4] = {};

    const int srow = lane >> 2;          // row within 16-row chunk (staging)
    const int scol = (lane & 3) * 8;     // 8-elem col group within 32-wide half
    const int k8 = (lane >> 4) * 8;      // fragment k-slice within 32-wide half
    const int fm = lane & 15;            // fragment row within 16

    for (int kt = 0; kt < EMBED; kt += 64) {
        #pragma unroll
        for (int t = 0; t < 2; ++t) {
            const int c = wave * 2 + t;          // 16-row chunk 0..7
            const int grow = c * 16 + srow;
            #pragma unroll
            for (int h = 0; h < 2; ++h) {        // two 32-wide k-halves
                const unsigned short* ga = A + (size_t)(m0 + grow) * EMBED + kt + h * 32 + scol;
                const unsigned short* gb = B + (size_t)(n0 + grow) * EMBED + kt + h * 32 + scol;
                __builtin_amdgcn_global_load_lds(
                    (const __attribute__((address_space(1))) void*)ga,
                    (__attribute__((address_space(3))) void*)(As + c * 1024 + h * 512), 16, 0, 0);
                __builtin_amdgcn_global_load_lds(
                    (const __attribute__((address_space(1))) void*)gb,
                    (__attribute__((address_space(3))) void*)(Bs + c * 1024 + h * 512), 16, 0, 0);
            }
        }
        __syncthreads();

        #pragma unroll
        for (int kk = 0; kk < 2; ++kk) {
            bf16x8 af[4], bfr[4];
            #pragma unroll
            for (int i = 0; i < 4; ++i) {
                const int ra = wm + i * 16 + fm;   // A row in tile
                const int rb = wn + i * 16 + fm;   // B row in tile
                af[i]  = *(const bf16x8*)(As + (ra >> 4) * 1024 + kk * 512 + (ra & 15) * 32 + k8);
                bfr[i] = *(const bf16x8*)(Bs + (rb >> 4) * 1024 + kk * 512 + (rb & 15) * 32 + k8);
            }
            #pragma unroll
            for (int i = 0; i < 4; ++i)
                #pragma unroll
                for (int j = 0; j < 4; ++j)
                    acc[i][j] = __builtin_amdgcn_mfma_f32_16x16x32_bf16(af[i], bfr[j], acc[i][j], 0, 0, 0);
        }
        __syncthreads();   // As/Bs dead after final iter -> Ct reuse below is safe
    }

    // ---- Epilogue: fragments -> Ct (bf16), then coalesced dwordx4 stores ----
    // C/D layout: col=lane&15, row=(lane>>4)*4+r
    const int col = lane & 15;
    const int rbase = (lane >> 4) * 4;
    #pragma unroll
    for (int i = 0; i < 4; ++i)
        #pragma unroll
        for (int j = 0; j < 4; ++j) {
            const int rr = wm + i * 16 + rbase;
            const int cc = wn + j * 16 + col;
            #pragma unroll
            for (int r = 0; r < 4; ++r)
                Ct[(rr + r) * CT_STRIDE + cc] = f2b(acc[i][j][r]);
        }
    __syncthreads();

    #pragma unroll
    for (int it = 0; it < 8; ++it) {
        const int r  = it * 16 + (tid >> 4);   // 0..127
        const int c8 = (tid & 15) * 8;         // 8-ushort chunk
        const int4 v = *(const int4*)(Ct + r * CT_STRIDE + c8);
        *(int4*)(D + (size_t)(m0 + r) * N + n0 + c8) = v;
    }
}

// ---------------- Phase 3: bilinear gather (LDS-staged D rows) + identity -------
__global__ __launch_bounds__(256) void gather_kernel(
    const unsigned short* __restrict__ D,   // [nq][nv] bf16
    const float* __restrict__ identity,     // [nq*128]
    const float* __restrict__ ref3d,        // [nq*128][2]
    const int*   __restrict__ spatial,      // {H, W}
    float* __restrict__ out, int nv)
{
    __shared__ unsigned short Ds[2 * 4096];  // 16 KB (nv <= 4096 guarded on host)

    const int q0 = blockIdx.x * 2;
    const int tid = threadIdx.x;

    const int4* src = (const int4*)(D + (size_t)q0 * nv);
    int4* dst = (int4*)Ds;
    const int nchunk = (2 * nv) / 8;
    for (int i = tid; i < nchunk; i += 256) dst[i] = src[i];
    __syncthreads();

    const int Hs = spatial[0], Ws = spatial[1];
    const int l = q0 * NUM_DEPTH + tid;      // 256 threads == 2 q * 128 d
    const int qi = tid >> 7;

    const float2 r2 = reinterpret_cast<const float2*>(ref3d)[l];
    const float px = r2.x * (float)Ws - 0.5f;
    const float py = r2.y * (float)Hs - 0.5f;
    const float x0f = floorf(px), y0f = floorf(py);
    const int ix0 = (int)x0f, iy0 = (int)y0f;
    const int ix1 = ix0 + 1,  iy1 = iy0 + 1;
    const float wx1 = px - x0f, wx0 = 1.0f - wx1;
    const float wy1 = py - y0f, wy0 = 1.0f - wy1;
    const bool vx0 = (ix0 >= 0) & (ix0 < Ws);
    const bool vx1 = (ix1 >= 0) & (ix1 < Ws);

    const unsigned short* row = Ds + qi * nv;
    float acc = 0.f;
    if (iy0 >= 0 && iy0 < Hs) {
        if (vx0) acc = fmaf(wy0 * wx0, b2f(row[iy0 * Ws + ix0]), acc);
        if (vx1) acc = fmaf(wy0 * wx1, b2f(row[iy0 * Ws + ix1]), acc);
    }
    if (iy1 >= 0 && iy1 < Hs) {
        if (vx0) acc = fmaf(wy1 * wx0, b2f(row[iy1 * Ws + ix0]), acc);
        if (vx1) acc = fmaf(wy1 * wx1, b2f(row[iy1 * Ws + ix1]), acc);
    }
    out[l] = fmaf(acc, 0.0625f, identity[l]);  // 1/sqrt(256) = 1/16
}

// ---------------- Fallback (round-1 direct kernel) ----------------
__global__ __launch_bounds__(256) void uv_direct_kernel(
    const float* __restrict__ key, const float* __restrict__ value,
    const float* __restrict__ identity, const float* __restrict__ ref3d,
    const int* __restrict__ spatial, float* __restrict__ out)
{
    const int q = blockIdx.x;
    const int tid = threadIdx.x;
    const int lane = tid & 63;
    const int wave = tid >> 6;
    const int H = spatial[0], W = spatial[1];
    const int row4 = EMBED / 4;
    const float4 k4 = reinterpret_cast<const float4*>(key + (size_t)q * EMBED)[lane];
    const float4* __restrict__ v4 = reinterpret_cast<const float4*>(value);
    for (int d = wave; d < NUM_DEPTH; d += 4) {
        const int l = q * NUM_DEPTH + d;
        const float rx = ref3d[2 * l], ry = ref3d[2 * l + 1];
        const float px = rx * (float)W - 0.5f, py = ry * (float)H - 0.5f;
        const float x0f = floorf(px), y0f = floorf(py);
        const int ix0 = (int)x0f, iy0 = (int)y0f, ix1 = ix0 + 1, iy1 = iy0 + 1;
        const float wx1 = px - x0f, wx0 = 1.f - wx1, wy1 = py - y0f, wy0 = 1.f - wy1;
        float4 acc = make_float4(0.f, 0.f, 0.f, 0.f);
        #define TAP(IY, IX, WGT) \
            if ((IY) >= 0 && (IY) < H && (IX) >= 0 && (IX) < W) { \
                const float w_ = (WGT); \
                const float4 t = v4[(size_t)((IY) * W + (IX)) * row4 + lane]; \
                acc.x = fmaf(w_, t.x, acc.x); acc.y = fmaf(w_, t.y, acc.y); \
                acc.z = fmaf(w_, t.z, acc.z); acc.w = fmaf(w_, t.w, acc.w); }
        TAP(iy0, ix0, wy0 * wx0) TAP(iy0, ix1, wy0 * wx1)
        TAP(iy1, ix0, wy1 * wx0) TAP(iy1, ix1, wy1 * wx1)
        #undef TAP
        float partial = acc.x * k4.x + acc.y * k4.y + acc.z * k4.z + acc.w * k4.w;
        #pragma unroll
        for (int off = 32; off > 0; off >>= 1) partial += __shfl_xor(partial, off, 64);
        if (lane == 0) out[l] = fmaf(partial, 0.0625f, identity[l]);
    }
}

extern "C" void kernel_launch(void* const* d_in, const int* in_sizes, int n_in,
                              void* d_out, int out_size, void* d_ws, size_t ws_size,
                              hipStream_t stream) {
    // inputs: 0 query(unused) 1 key 2 value 3 identity 4 ref_3d 5 spatial 6 W_attn(unused) 7 b_attn(unused)
    const float* key      = (const float*)d_in[1];
    const float* value    = (const float*)d_in[2];
    const float* identity = (const float*)d_in[3];
    const float* ref3d    = (const float*)d_in[4];
    const int*   spatial  = (const int*)d_in[5];
    float* out = (float*)d_out;

    const int nq = in_sizes[3] / NUM_DEPTH;   // 4096 queries
    const int nv = in_sizes[1] / EMBED;       // 4096 pixels (= H*W)

    const size_t d_bytes  = (size_t)nq * nv * sizeof(unsigned short);
    const size_t kb_bytes = (size_t)nq * EMBED * sizeof(unsigned short);
    const size_t vb_bytes = (size_t)nv * EMBED * sizeof(unsigned short);
    const size_t need = d_bytes + kb_bytes + vb_bytes;

    if (ws_size < need || (nq % 128) || (nv % 128) || nv > 4096 || (nq % 2)) {
        uv_direct_kernel<<<nq, 256, 0, stream>>>(key, value, identity, ref3d, spatial, out);
        return;
    }

    unsigned short* D  = (unsigned short*)d_ws;
    unsigned short* kb = (unsigned short*)((char*)d_ws + d_bytes);
    unsigned short* vb = (unsigned short*)((char*)d_ws + d_bytes + kb_bytes);

    // Phase 1: convert key & value to bf16
    const int n4 = nq * EMBED / 4;
    cvt_kernel<<<(n4 + 255) / 256, 256, 0, stream>>>(
        (const float4*)key, (const float4*)value, (ushort4*)kb, (ushort4*)vb, n4);

    // Phase 2: D = key . value^T
    dim3 grid(nv / 128, nq / 128);
    gemm_nt_bf16<<<grid, 256, 0, stream>>>(kb, vb, D, nv);

    // Phase 3: bilinear gather + identity (2 queries per block)
    gather_kernel<<<nq / 2, 256, 0, stream>>>(D, identity, ref3d, spatial, out, nv);
}